// Round 6
// baseline (38.055 us; speedup 1.0000x reference)
//
#include <hip/hip_runtime.h>
#include <math.h>

#define CIN   8
#define COUT  8
#define HH    16
#define NN    400
#define MM    400
#define BB    16

#define THREADS 512    // 8 waves
#define GM      2      // m's per pg (slot page = 64 = GM*PMAX)
#define PMAX    32     // padded slots per m (worst-case inside count ~26)
#define NPG     (MM/GM)   // 200 m-groups

// ws layout (floats):
//   ft[NN*CIN*BB]          : ft[n*128 + i*16 + b] = f[b][i][n]          (51200)
//   lst[MM*PMAX*4]         : per slot float4 {zx, zy, bw, as_float(n)}  (51200)
#define WS_FT 0
#define WS_L  (NN*CIN*BB)

// ---------------- kernel 1: feature transpose + inside-lists ----------------
__global__ __launch_bounds__(THREADS) void prep_kernel(
    const float* __restrict__ f,      // (B, CIN, NN)
    const float* __restrict__ locs,   // (MM, 2)
    const float* __restrict__ nodes,  // (NN, 2)
    const float* __restrict__ wq,     // (NN,)
    float* __restrict__ ws)
{
    const int blk = blockIdx.x;
    const int t   = threadIdx.x;

    if (blk < 100) {
        // transpose, read-coalesced: idx walks f linearly
        int idx = blk * 512 + t;              // = b*3200 + i*400 + n
        int b = idx / 3200;
        int r = idx - b * 3200;
        int i = r / 400;
        int n = r - i * 400;
        ws[WS_FT + n*128 + i*16 + b] = f[idx];
    } else {
        // inside-lists: 50 blocks x 8 waves, one m per wave
        const int lane = t & 63;
        const int w    = t >> 6;
        const int m    = (blk - 100) * 8 + w;
        const float2 y = ((const float2*)locs)[m];
        const float2* nd = (const float2*)nodes;
        float4* lst = (float4*)(ws + WS_L);
        int cnt = 0;
        for (int n0 = 0; n0 < NN; n0 += 64) {
            int n = n0 + lane;
            bool in = false;
            float zx = 0.f, zy = 0.f, bwv = 0.f;
            if (n < NN) {
                float2 x = nd[n];
                zx = y.x - x.x; zy = y.y - x.y;
                float s = zx*zx + zy*zy;
                float a = s * s;                    // ||z||^4
                if (a < (1.0f/625.0f)) {
                    in = true;
                    bwv = __expf(1.0f - 1.0f/(1.0f - 625.0f*a)) * wq[n];
                }
            }
            unsigned long long msk = __ballot(in);
            int idx = cnt + __popcll(msk & ((1ull << lane) - 1ull));
            if (in && idx < PMAX)
                lst[m*PMAX + idx] = make_float4(zx, zy, bwv, __int_as_float(n));
            cnt += __popcll(msk);
        }
        if (lane >= cnt && lane < PMAX)
            lst[m*PMAX + lane] = make_float4(0.f, 0.f, 0.f, __int_as_float(0));
    }
}

// ---------------- kernel 2: MLP eval + contraction (persistent blocks) ------
// grid = 512: kg = bid>>6 (output channel o), pb = bid&63.
// wave w: k = kg*8 + w (fixed all iterations) -> o = kg, i = w.
// block loops pg in {pb, pb+64, pb+128, pb+192<200}; slots = 64 (2 m x 32).
__global__ __launch_bounds__(THREADS, 8) void quadconv_kernel(
    const float* __restrict__ W1,     // (K, H, 2)
    const float* __restrict__ W2,     // (K, H, H)
    const float* __restrict__ W3,     // (K, 1, H)
    const float* __restrict__ ws,     // ft + lists
    float* __restrict__ out)          // (B, COUT, MM)
{
    __shared__ float s_kv[8*64];      // [wave][slot]
    __shared__ float s_part[8*32];    // [wave][g*16+b]
    __shared__ int   s_pn[2][64];     // double-buffered node ids

    const int t    = threadIdx.x;
    const int lane = t & 63;
    const int w    = __builtin_amdgcn_readfirstlane(t >> 6);
    const int kg   = blockIdx.x >> 6;     // 0..7
    const int pb   = blockIdx.x & 63;     // 0..63

    const int k = kg * 8 + w;
    const float* __restrict__ w1 = W1 + k * (HH * 2);
    const float* __restrict__ w2 = W2 + k * (HH * HH);
    const float* __restrict__ w3 = W3 + k * HH;

    const int b    = lane & 15;
    const int g    = (lane >> 4) & 1;
    const int half = lane >> 5;
    const float* __restrict__ ftp = ws + WS_FT;
    const float4* __restrict__ lst = (const float4*)(ws + WS_L);

    // prologue: load first page's slot data
    int pg = pb;
    float4 sv = lst[pg*64 + lane];
    if (t < 64) s_pn[0][t] = __float_as_int(sv.w);
    __syncthreads();

    int par = 0;
    for (; pg < NPG; pg += 64, par ^= 1) {
        // ---- Phase B: per-wave MLP, k wave-uniform, lane = slot ----
        {
            const float zx = sv.x, zy = sv.y, bw = sv.z;
            float h1[HH];
            #pragma unroll
            for (int j = 0; j < HH; ++j)
                h1[j] = __sinf(w1[2*j] * zx + w1[2*j + 1] * zy);

            float kv = 0.f;
            #pragma unroll
            for (int oo = 0; oo < HH; ++oo) {
                float d = 0.f;
                #pragma unroll
                for (int j = 0; j < HH; ++j)
                    d += w2[oo*HH + j] * h1[j];
                kv += w3[oo] * __sinf(d);
            }
            s_kv[w*64 + lane] = kv * bw;
        }

        // ---- prefetch next page (overlaps phase C) ----
        const int pgN = pg + 64;
        float4 svN = make_float4(0.f, 0.f, 0.f, 0.f);
        if (pgN < NPG) svN = lst[pgN*64 + lane];

        __syncthreads();   // s_kv ready (s_pn[par] already valid)

        // ---- Phase C: contraction on transposed features ----
        {
            float acc = 0.f;
            #pragma unroll
            for (int jj = 0; jj < PMAX/2; ++jj) {
                int   sl = g*PMAX + half*(PMAX/2) + jj;
                int   n  = s_pn[par][sl];
                acc += s_kv[w*64 + sl] * ftp[n*128 + w*16 + b];   // i = w
            }
            acc += __shfl_xor(acc, 32);
            if (half == 0)
                s_part[w*32 + lane] = acc;    // lane = g*16 + b
        }
        if (pgN < NPG && t < 64) s_pn[par ^ 1][t] = __float_as_int(svN.w);

        __syncthreads();   // s_part ready, s_pn[par^1] ready

        // ---- Final: sum over i (=wave) and store ----
        if (t < 32) {
            const int bb = t & 15, gg = t >> 4;
            float v = 0.f;
            #pragma unroll
            for (int ww = 0; ww < 8; ++ww)
                v += s_part[ww*32 + t];
            out[bb * (COUT*MM) + kg * MM + (pg*GM + gg)] = v;
        }
        sv = svN;
        // next iteration's s_part writes are ordered after its own
        // s_kv barrier, which follows the t<32 reads above -> no extra barrier
    }
}

extern "C" void kernel_launch(void* const* d_in, const int* in_sizes, int n_in,
                              void* d_out, int out_size, void* d_ws, size_t ws_size,
                              hipStream_t stream) {
    const float* f     = (const float*)d_in[0];
    const float* W1    = (const float*)d_in[1];
    const float* W2    = (const float*)d_in[2];
    const float* W3    = (const float*)d_in[3];
    const float* locs  = (const float*)d_in[4];
    const float* nodes = (const float*)d_in[5];
    const float* wq    = (const float*)d_in[6];
    float* out = (float*)d_out;
    float* ws  = (float*)d_ws;

    prep_kernel<<<dim3(150), dim3(THREADS), 0, stream>>>(f, locs, nodes, wq, ws);
    quadconv_kernel<<<dim3(512), dim3(THREADS), 0, stream>>>(W1, W2, W3, ws, out);
}

// Round 7
// 23.348 us; speedup vs baseline: 1.6299x; 1.6299x over previous
//
#include <hip/hip_runtime.h>
#include <math.h>

#define CIN   8
#define COUT  8
#define HH    16
#define NN    400
#define MM    400
#define BB    16

#define THREADS 512    // 8 waves
#define GM      2      // m's per block
#define PMAX    32     // padded slots per m (worst-case inside count ~26)

// ws layout (floats):
//   ft[NN*CIN*BB]   : ft[n*128 + i*16 + b] = f[b][i][n]            (51200)
//   lst[MM*PMAX*4]  : per slot float4 {zx, zy, bw, as_float(n)}    (51200)
#define WS_FT 0
#define WS_L  (NN*CIN*BB)

// ---------------- kernel 1: feature transpose + inside-lists ----------------
__global__ __launch_bounds__(THREADS) void prep_kernel(
    const float* __restrict__ f,      // (B, CIN, NN)
    const float* __restrict__ locs,   // (MM, 2)
    const float* __restrict__ nodes,  // (NN, 2)
    const float* __restrict__ wq,     // (NN,)
    float* __restrict__ ws)
{
    const int blk = blockIdx.x;
    const int t   = threadIdx.x;

    if (blk < 100) {
        // transpose, read-coalesced: idx walks f linearly
        int idx = blk * 512 + t;              // = b*3200 + i*400 + n
        int b = idx / 3200;
        int r = idx - b * 3200;
        int i = r / 400;
        int n = r - i * 400;
        ws[WS_FT + n*128 + i*16 + b] = f[idx];
    } else {
        // inside-lists: 50 blocks x 8 waves, one m per wave
        const int lane = t & 63;
        const int w    = t >> 6;
        const int m    = (blk - 100) * 8 + w;
        const float2 y = ((const float2*)locs)[m];
        const float2* nd = (const float2*)nodes;
        float4* lst = (float4*)(ws + WS_L);
        int cnt = 0;
        for (int n0 = 0; n0 < NN; n0 += 64) {
            int n = n0 + lane;
            bool in = false;
            float zx = 0.f, zy = 0.f, bwv = 0.f;
            if (n < NN) {
                float2 x = nd[n];
                zx = y.x - x.x; zy = y.y - x.y;
                float s = zx*zx + zy*zy;
                float a = s * s;                    // ||z||^4
                if (a < (1.0f/625.0f)) {
                    in = true;
                    bwv = __expf(1.0f - 1.0f/(1.0f - 625.0f*a)) * wq[n];
                }
            }
            unsigned long long msk = __ballot(in);
            int idx = cnt + __popcll(msk & ((1ull << lane) - 1ull));
            if (in && idx < PMAX)
                lst[m*PMAX + idx] = make_float4(zx, zy, bwv, __int_as_float(n));
            cnt += __popcll(msk);
        }
        if (lane >= cnt && lane < PMAX)
            lst[m*PMAX + lane] = make_float4(0.f, 0.f, 0.f, __int_as_float(0));
    }
}

// ---------------- kernel 2: MLP eval + contraction ----------------
// grid = (MM/GM) * COUT = 200 * 8 = 1600 blocks
// block (pg, kg): m in [pg*2, pg*2+2), output channel o = kg.
// wave w (0..7): k = kg*8 + w  ->  o = kg, i = w.
// Weights for all 8 k's staged in LDS; phase-B reads are wave-uniform
// broadcasts (ds_read_b128), eliminating the SGPR s_load refill stalls.
__global__ __launch_bounds__(THREADS, 4) void quadconv_kernel(
    const float* __restrict__ W1,     // (K, H, 2)
    const float* __restrict__ W2,     // (K, H, H)
    const float* __restrict__ W3,     // (K, 1, H)
    const float* __restrict__ ws,     // ft + lists
    float* __restrict__ out)          // (B, COUT, MM)
{
    __shared__ float s_w2[8*256];     // [k_local][oo*16+j]
    __shared__ float s_w1[8*32];      // [k_local][j*2+d]
    __shared__ float s_w3[8*16];      // [k_local][oo]
    __shared__ float s_kv[8*64];      // [wave][slot]
    __shared__ float s_part[8*32];    // [wave][g*16+b]
    __shared__ int   s_pn[64];        // node ids per slot

    const int t    = threadIdx.x;
    const int lane = t & 63;
    const int w    = __builtin_amdgcn_readfirstlane(t >> 6);
    const int pg   = blockIdx.x >> 3;
    const int kg   = blockIdx.x & 7;
    const int m0   = pg * GM;

    // ---- stage this block's 8 weight sets into LDS (one float4/thread) ----
    {
        const float4* W2v = (const float4*)(W2 + kg * 8 * 256);   // 512 float4
        ((float4*)s_w2)[t] = W2v[t];
        if (t < 64) ((float4*)s_w1)[t] = ((const float4*)(W1 + kg * 8 * 32))[t];
        if (t < 32) ((float4*)s_w3)[t] = ((const float4*)(W3 + kg * 8 * 16))[t];
    }

    // lane = slot (2 m's x 32 padded slots); one coalesced float4 per lane
    const float4 sv = ((const float4*)(ws + WS_L))[pg*64 + lane];
    if (t < 64) s_pn[t] = __float_as_int(sv.w);
    __syncthreads();

    // ---- Phase B: per-wave MLP from LDS weights, lane = slot ----
    {
        const float* __restrict__ w1 = s_w1 + w * 32;
        const float* __restrict__ w2 = s_w2 + w * 256;
        const float* __restrict__ w3 = s_w3 + w * 16;
        const float zx = sv.x, zy = sv.y, bw = sv.z;

        float h1[HH];
        #pragma unroll
        for (int j = 0; j < HH; ++j)
            h1[j] = __sinf(w1[2*j] * zx + w1[2*j + 1] * zy);

        float kv = 0.f;
        #pragma unroll
        for (int oo = 0; oo < HH; ++oo) {
            float d = 0.f;
            #pragma unroll
            for (int j = 0; j < HH; ++j)
                d += w2[oo*HH + j] * h1[j];
            kv += w3[oo] * __sinf(d);
        }
        s_kv[w*64 + lane] = kv * bw;
    }
    __syncthreads();

    // ---- Phase C: contraction on transposed features ----
    // lane = (half, g, b); 16 j-terms per lane; ft loads hit 4x64B lines
    {
        const int b    = lane & 15;
        const int g    = (lane >> 4) & 1;
        const int half = lane >> 5;
        const float* __restrict__ ftp = ws + WS_FT;
        float acc = 0.f;
        #pragma unroll
        for (int jj = 0; jj < PMAX/2; ++jj) {
            int   sl = g*PMAX + half*(PMAX/2) + jj;
            int   n  = s_pn[sl];
            acc += s_kv[w*64 + sl] * ftp[n*128 + w*16 + b];   // i = w
        }
        acc += __shfl_xor(acc, 32);       // combine the two halves
        if (half == 0)
            s_part[w*32 + lane] = acc;    // lane = g*16 + b
    }
    __syncthreads();

    // ---- Final: sum over i (=wave) and store ----
    if (t < 32) {
        const int b = t & 15, g = t >> 4;
        float v = 0.f;
        #pragma unroll
        for (int ww = 0; ww < 8; ++ww)
            v += s_part[ww*32 + t];
        out[b * (COUT*MM) + kg * MM + (m0 + g)] = v;
    }
}

extern "C" void kernel_launch(void* const* d_in, const int* in_sizes, int n_in,
                              void* d_out, int out_size, void* d_ws, size_t ws_size,
                              hipStream_t stream) {
    const float* f     = (const float*)d_in[0];
    const float* W1    = (const float*)d_in[1];
    const float* W2    = (const float*)d_in[2];
    const float* W3    = (const float*)d_in[3];
    const float* locs  = (const float*)d_in[4];
    const float* nodes = (const float*)d_in[5];
    const float* wq    = (const float*)d_in[6];
    float* out = (float*)d_out;
    float* ws  = (float*)d_ws;

    prep_kernel<<<dim3(150), dim3(THREADS), 0, stream>>>(f, locs, nodes, wq, ws);
    quadconv_kernel<<<dim3((MM/GM) * COUT), dim3(THREADS), 0, stream>>>(
        W1, W2, W3, ws, out);
}